// Round 2
// baseline (421.363 us; speedup 1.0000x reference)
//
#include <hip/hip_runtime.h>

#define DD 160
#define HH 192
#define WW 160
#define VOL (DD * HH * WW)   // 4915200
#define NB 2
#define NC 2

// 4 consecutive W-voxels per thread. VOL % 4 == 0 and WW % 4 == 0, so a
// 4-group never crosses a row boundary and float4 loads/stores are aligned.
__global__ __launch_bounds__(256) void warp_kernel(
    const float* __restrict__ x,
    const float* __restrict__ flow,
    float* __restrict__ out)
{
    int t = blockIdx.x * blockDim.x + threadIdx.x;
    int v = t * 4;                       // global voxel index (incl. batch)
    int b = (v >= VOL) ? 1 : 0;
    v -= b * VOL;

    int xw = v % WW;                     // first of 4 x-positions
    int tt = v / WW;
    int yh = tt % HH;
    int zd = tt / HH;

    const float* fb = flow + (size_t)b * 3 * VOL;
    float4 dz4 = *(const float4*)(fb + v);
    float4 dy4 = *(const float4*)(fb + v + VOL);
    float4 dx4 = *(const float4*)(fb + v + 2 * VOL);

    float pz[4] = { zd + dz4.x, zd + dz4.y, zd + dz4.z, zd + dz4.w };
    float py[4] = { yh + dy4.x, yh + dy4.y, yh + dy4.z, yh + dy4.w };
    float px[4] = { (float)xw + dx4.x, (float)(xw + 1) + dx4.y,
                    (float)(xw + 2) + dx4.z, (float)(xw + 3) + dx4.w };

    int   idx[4][8];
    float wgt[4][8];

#pragma unroll
    for (int j = 0; j < 4; ++j) {
        float z0f = floorf(pz[j]), y0f = floorf(py[j]), x0f = floorf(px[j]);
        float fz = pz[j] - z0f, fy = py[j] - y0f, fx = px[j] - x0f;
        int z0 = (int)z0f, y0 = (int)y0f, x0 = (int)x0f;
        int z1 = z0 + 1,  y1 = y0 + 1,  x1 = x0 + 1;

        float wz0 = (z0 >= 0 && z0 < DD) ? (1.0f - fz) : 0.0f;
        float wz1 = (z1 >= 0 && z1 < DD) ? fz : 0.0f;
        float wy0 = (y0 >= 0 && y0 < HH) ? (1.0f - fy) : 0.0f;
        float wy1 = (y1 >= 0 && y1 < HH) ? fy : 0.0f;
        float wx0 = (x0 >= 0 && x0 < WW) ? (1.0f - fx) : 0.0f;
        float wx1 = (x1 >= 0 && x1 < WW) ? fx : 0.0f;

        int z0c = min(max(z0, 0), DD - 1);
        int z1c = min(max(z1, 0), DD - 1);
        int y0c = min(max(y0, 0), HH - 1);
        int y1c = min(max(y1, 0), HH - 1);
        int x0c = min(max(x0, 0), WW - 1);
        int x1c = min(max(x1, 0), WW - 1);

        int p00 = (z0c * HH + y0c) * WW;
        int p01 = (z0c * HH + y1c) * WW;
        int p10 = (z1c * HH + y0c) * WW;
        int p11 = (z1c * HH + y1c) * WW;

        idx[j][0] = p00 + x0c;  wgt[j][0] = wz0 * wy0 * wx0;
        idx[j][1] = p00 + x1c;  wgt[j][1] = wz0 * wy0 * wx1;
        idx[j][2] = p01 + x0c;  wgt[j][2] = wz0 * wy1 * wx0;
        idx[j][3] = p01 + x1c;  wgt[j][3] = wz0 * wy1 * wx1;
        idx[j][4] = p10 + x0c;  wgt[j][4] = wz1 * wy0 * wx0;
        idx[j][5] = p10 + x1c;  wgt[j][5] = wz1 * wy0 * wx1;
        idx[j][6] = p11 + x0c;  wgt[j][6] = wz1 * wy1 * wx0;
        idx[j][7] = p11 + x1c;  wgt[j][7] = wz1 * wy1 * wx1;
    }

    const float* xb0 = x + (size_t)b * NC * VOL;
    const float* xb1 = xb0 + VOL;

    float a0[4], a1[4];
#pragma unroll
    for (int j = 0; j < 4; ++j) {
        float s0 = 0.0f, s1 = 0.0f;
#pragma unroll
        for (int k = 0; k < 8; ++k) {
            float w  = wgt[j][k];
            int   ii = idx[j][k];
            s0 += w * xb0[ii];
            s1 += w * xb1[ii];
        }
        a0[j] = s0;
        a1[j] = s1;
    }

    float* ob = out + (size_t)b * NC * VOL;
    *(float4*)(ob + v)       = make_float4(a0[0], a0[1], a0[2], a0[3]);
    *(float4*)(ob + v + VOL) = make_float4(a1[0], a1[1], a1[2], a1[3]);
}

extern "C" void kernel_launch(void* const* d_in, const int* in_sizes, int n_in,
                              void* d_out, int out_size, void* d_ws, size_t ws_size,
                              hipStream_t stream) {
    const float* x    = (const float*)d_in[0];
    const float* flow = (const float*)d_in[1];
    float* out        = (float*)d_out;

    int total_threads = NB * VOL / 4;    // 2,457,600
    int block = 256;
    int grid  = (total_threads + block - 1) / block;  // 9600
    warp_kernel<<<grid, block, 0, stream>>>(x, flow, out);
}

// Round 4
// 373.126 us; speedup vs baseline: 1.1293x; 1.1293x over previous
//
#include <hip/hip_runtime.h>

#define DD 160
#define HH 192
#define WW 160
#define VOL (DD * HH * WW)   // 4915200
#define NB 2
#define NC 2

typedef float v2f __attribute__((ext_vector_type(2)));

// 2 consecutive W-voxels per thread, fully scalar live state (no spill).
// Flow is streamed with nontemporal loads to preserve L2 for x gathers.
__global__ __launch_bounds__(256) void warp_kernel(
    const float* __restrict__ x,
    const float* __restrict__ flow,
    float* __restrict__ out)
{
    int t = blockIdx.x * blockDim.x + threadIdx.x;
    int v = t * 2;                       // global voxel index (incl. batch)
    int b = (v >= VOL) ? 1 : 0;
    v -= b * VOL;

    int xw = v % WW;                     // first of 2 x-positions
    int tt = v / WW;
    int yh = tt % HH;
    int zd = tt / HH;

    const float* fb = flow + (size_t)b * 3 * VOL;
    v2f dz2 = __builtin_nontemporal_load((const v2f*)(fb + v));
    v2f dy2 = __builtin_nontemporal_load((const v2f*)(fb + v + VOL));
    v2f dx2 = __builtin_nontemporal_load((const v2f*)(fb + v + 2 * VOL));

    float pz[2] = { zd + dz2.x, zd + dz2.y };
    float py[2] = { yh + dy2.x, yh + dy2.y };
    float px[2] = { xw + dx2.x, (xw + 1) + dx2.y };

    int   idx[2][8];
    float wgt[2][8];

#pragma unroll
    for (int j = 0; j < 2; ++j) {
        float z0f = floorf(pz[j]), y0f = floorf(py[j]), x0f = floorf(px[j]);
        float fz = pz[j] - z0f, fy = py[j] - y0f, fx = px[j] - x0f;
        int z0 = (int)z0f, y0 = (int)y0f, x0 = (int)x0f;
        int z1 = z0 + 1,  y1 = y0 + 1,  x1 = x0 + 1;

        float wz0 = (z0 >= 0 && z0 < DD) ? (1.0f - fz) : 0.0f;
        float wz1 = (z1 >= 0 && z1 < DD) ? fz : 0.0f;
        float wy0 = (y0 >= 0 && y0 < HH) ? (1.0f - fy) : 0.0f;
        float wy1 = (y1 >= 0 && y1 < HH) ? fy : 0.0f;
        float wx0 = (x0 >= 0 && x0 < WW) ? (1.0f - fx) : 0.0f;
        float wx1 = (x1 >= 0 && x1 < WW) ? fx : 0.0f;

        int z0c = min(max(z0, 0), DD - 1);
        int z1c = min(max(z1, 0), DD - 1);
        int y0c = min(max(y0, 0), HH - 1);
        int y1c = min(max(y1, 0), HH - 1);
        int x0c = min(max(x0, 0), WW - 1);
        int x1c = min(max(x1, 0), WW - 1);

        int p00 = (z0c * HH + y0c) * WW;
        int p01 = (z0c * HH + y1c) * WW;
        int p10 = (z1c * HH + y0c) * WW;
        int p11 = (z1c * HH + y1c) * WW;

        idx[j][0] = p00 + x0c;  wgt[j][0] = wz0 * wy0 * wx0;
        idx[j][1] = p00 + x1c;  wgt[j][1] = wz0 * wy0 * wx1;
        idx[j][2] = p01 + x0c;  wgt[j][2] = wz0 * wy1 * wx0;
        idx[j][3] = p01 + x1c;  wgt[j][3] = wz0 * wy1 * wx1;
        idx[j][4] = p10 + x0c;  wgt[j][4] = wz1 * wy0 * wx0;
        idx[j][5] = p10 + x1c;  wgt[j][5] = wz1 * wy0 * wx1;
        idx[j][6] = p11 + x0c;  wgt[j][6] = wz1 * wy1 * wx0;
        idx[j][7] = p11 + x1c;  wgt[j][7] = wz1 * wy1 * wx1;
    }

    const float* xb0 = x + (size_t)b * NC * VOL;
    const float* xb1 = xb0 + VOL;

    float a0[2], a1[2];
#pragma unroll
    for (int j = 0; j < 2; ++j) {
        float s0 = 0.0f, s1 = 0.0f;
#pragma unroll
        for (int k = 0; k < 8; ++k) {
            float w  = wgt[j][k];
            int   ii = idx[j][k];
            s0 += w * xb0[ii];
            s1 += w * xb1[ii];
        }
        a0[j] = s0;
        a1[j] = s1;
    }

    float* ob = out + (size_t)b * NC * VOL;
    v2f r0; r0.x = a0[0]; r0.y = a0[1];
    v2f r1; r1.x = a1[0]; r1.y = a1[1];
    __builtin_nontemporal_store(r0, (v2f*)(ob + v));
    __builtin_nontemporal_store(r1, (v2f*)(ob + v + VOL));
}

extern "C" void kernel_launch(void* const* d_in, const int* in_sizes, int n_in,
                              void* d_out, int out_size, void* d_ws, size_t ws_size,
                              hipStream_t stream) {
    const float* x    = (const float*)d_in[0];
    const float* flow = (const float*)d_in[1];
    float* out        = (float*)d_out;

    int total_threads = NB * VOL / 2;    // 4,915,200
    int block = 256;
    int grid  = (total_threads + block - 1) / block;  // 19200
    warp_kernel<<<grid, block, 0, stream>>>(x, flow, out);
}